// Round 5
// baseline (279.449 us; speedup 1.0000x reference)
//
#include <hip/hip_runtime.h>
#include <hip/hip_bf16.h>

#define N_NODES 100000
#define N_EDGES 1000000
#define CH 128
#define KTOT 256
#define NCLS 3

#define NBKT 196                    // coarse buckets: dst>>9
#define EPB 4096                    // edges per partition block (parallelism!)
#define NB_A ((N_EDGES + EPB - 1) / EPB)          // 245
#define M_H (NBKT * NB_A)                          // 48020
#define NB_SCAN ((M_H + 1023) / 1024)              // 47 co-resident blocks

#define NB_CVTX (N_NODES * CH / 4 / 256)           // 12500
#define NB_CVTW (KTOT * CH / 256)                  // 128
#define NB_A1 (NB_A + NB_CVTX + 2 * NB_CVTW)       // 13001

typedef __attribute__((ext_vector_type(8))) short v8s;   // 8 bf16 (A/B frag)
typedef __attribute__((ext_vector_type(4))) float v4f;   // 4 f32 (C/D frag)

__device__ __forceinline__ float bf2f(unsigned short u) {
    return __uint_as_float(((unsigned int)u) << 16);
}

__device__ __forceinline__ unsigned short f2bf(float f) {  // RNE
    unsigned int u = __float_as_uint(f);
    unsigned int r = (u + 0x7fffu + ((u >> 16) & 1u)) >> 16;
    return (unsigned short)r;
}

__device__ __forceinline__ int edge_at(const void* e, int is64, long long i) {
    if (is64) return (int)((const long long*)e)[i];
    return ((const int*)e)[i];
}

__device__ __forceinline__ float ldf(const void* p, int isbf, size_t i) {
    if (isbf) return bf2f(((const unsigned short*)p)[i]);
    return ((const float*)p)[i];
}

__device__ __forceinline__ void acc_u32(unsigned int u, float& a0, float& a1) {
    a0 += bf2f((unsigned short)(u & 0xffffu));
    a1 += bf2f((unsigned short)(u >> 16));
}

// --- K0: dtype sniffers + done flag ---
__global__ void k_init(const void* __restrict__ e, const unsigned int* __restrict__ x,
                       int* __restrict__ eflag, int* __restrict__ dtf,
                       int* __restrict__ done) {
    if (blockIdx.x == 0) {
        if (threadIdx.x < 64) {
            int v = ((const int*)e)[2 * threadIdx.x + 1];
            unsigned long long bl = __ballot(v != 0);
            if (threadIdx.x == 0) *eflag = (bl == 0ULL) ? 1 : 0;
        } else if (threadIdx.x == 64) {
            *done = 0;
        }
    } else {
        if (threadIdx.x < 64) {
            unsigned int u = x[threadIdx.x];
            int ex = (u >> 7) & 0xff;
            int sane = (ex == 0) || (ex >= 100 && ex <= 154);
            unsigned long long bl = __ballot(sane);
            if (threadIdx.x == 0) *dtf = (__popcll(bl) >= 48) ? 1 : 0;
        }
    }
}

// --- K1: coarse-bucket histogram (LDS atomics only) interleaved with cvt.
// x converts to a DENSE [N][128] bf16 buffer. ---
__global__ void k_A1(const void* __restrict__ e, const int* __restrict__ eflag,
                     const int* __restrict__ dtf, int* __restrict__ hist,
                     const void* __restrict__ x, unsigned short* __restrict__ Xb,
                     const void* __restrict__ wl1, const void* __restrict__ wr1,
                     unsigned short* __restrict__ WT1,
                     const void* __restrict__ wl2, const void* __restrict__ wr2,
                     unsigned short* __restrict__ WT2) {
    int b = blockIdx.x;
    int t = threadIdx.x;
    if (b < NB_A) {
        __shared__ int h[NBKT];
        if (t < NBKT) h[t] = 0;
        __syncthreads();
        int is64 = *eflag;
#pragma unroll
        for (int j = 0; j < EPB / 256; j++) {
            int i = b * EPB + j * 256 + t;
            if (i < N_EDGES) {
                int dst = edge_at(e, is64, (long long)N_EDGES + i);
                atomicAdd(&h[dst >> 9], 1);
            }
        }
        __syncthreads();
        if (t < NBKT) hist[t * NB_A + b] = h[t];
    } else {
        int ob = b - NB_A;
        if (ob < NB_CVTX) {
            int idx = ob * 256 + t;
            int node = idx >> 5;
            int ch = (idx & 31) * 4;
            int isbf = *dtf;
            unsigned short o[4];
            if (isbf) {
                ushort4 u = *(const ushort4*)((const unsigned short*)x +
                                              (size_t)node * CH + ch);
                o[0] = u.x; o[1] = u.y; o[2] = u.z; o[3] = u.w;
            } else {
                float4 v = *(const float4*)((const float*)x + (size_t)node * CH + ch);
                o[0] = f2bf(v.x); o[1] = f2bf(v.y); o[2] = f2bf(v.z); o[3] = f2bf(v.w);
            }
            *(ushort4*)(Xb + (size_t)node * CH + ch) =
                make_ushort4(o[0], o[1], o[2], o[3]);
        } else {
            int rel = ob - NB_CVTX;
            const void* wl = (rel < NB_CVTW) ? wl1 : wl2;
            const void* wr = (rel < NB_CVTW) ? wr1 : wr2;
            unsigned short* WT = (rel < NB_CVTW) ? WT1 : WT2;
            int i = (rel % NB_CVTW) * 256 + t;
            int k = i >> 7;
            int n = i & 127;
            int isbf = *dtf;
            float v = (k < CH) ? ldf(wl, isbf, (size_t)k * CH + n)
                               : ldf(wr, isbf, (size_t)(k - CH) * CH + n);
            WT[(size_t)n * KTOT + k] = f2bf(v);
        }
    }
}

// --- K2: multi-block exclusive scan, producer-only spin barrier ---
__global__ __launch_bounds__(1024) void k_scanH(int* __restrict__ hist,
                                                int* __restrict__ bsum,
                                                int* __restrict__ done) {
    __shared__ int s[1024];
    __shared__ int pre_sh;
    int t = threadIdx.x, b = blockIdx.x;
    int idx = b * 1024 + t;
    int v = (idx < M_H) ? hist[idx] : 0;
    s[t] = v;
    __syncthreads();
    for (int off = 1; off < 1024; off <<= 1) {
        int u = (t >= off) ? s[t - off] : 0;
        __syncthreads();
        s[t] += u;
        __syncthreads();
    }
    if (t == 1023) {
        bsum[b] = s[t];
        __threadfence();
        atomicAdd(done, 1);
    }
    if (t == 0) {
        while (__hip_atomic_load(done, __ATOMIC_ACQUIRE,
                                 __HIP_MEMORY_SCOPE_AGENT) < NB_SCAN) {
        }
        __threadfence();
        int run = 0;
        for (int r = 0; r < b; r++) run += bsum[r];
        pre_sh = run;
    }
    __syncthreads();
    if (idx < M_H) hist[idx] = s[t] - v + pre_sh;  // exclusive
}

// --- K3: partition scatter via LDS cursors; pack (src<<9)|(dst&511) ---
__global__ void k_A3(const void* __restrict__ e, const int* __restrict__ eflag,
                     const int* __restrict__ hist, unsigned int* __restrict__ part) {
    __shared__ int cur[NBKT];
    int b = blockIdx.x;
    int t = threadIdx.x;
    if (t < NBKT) cur[t] = hist[t * NB_A + b];
    __syncthreads();
    int is64 = *eflag;
#pragma unroll
    for (int j = 0; j < EPB / 256; j++) {
        int i = b * EPB + j * 256 + t;
        if (i < N_EDGES) {
            int src = edge_at(e, is64, i);
            int dst = edge_at(e, is64, (long long)N_EDGES + i);
            int pos = atomicAdd(&cur[dst >> 9], 1);  // LDS atomic
            part[pos] = ((unsigned int)src << 9) | (unsigned int)(dst & 511);
        }
    }
}

// --- K4: per-bucket finalize: degree count + scan -> row_start + csr_src ---
__global__ __launch_bounds__(1024) void k_B(const int* __restrict__ hist,
                                            const unsigned int* __restrict__ part,
                                            int* __restrict__ row_start,
                                            int* __restrict__ csr_src) {
    __shared__ int dcnt[512], sa[512], curs[512];
    int b = blockIdx.x;
    int t = threadIdx.x;
    int e0 = hist[b * NB_A];
    int e1 = (b + 1 < NBKT) ? hist[(b + 1) * NB_A] : N_EDGES;
    if (t < 512) dcnt[t] = 0;
    __syncthreads();
    for (int i = e0 + t; i < e1; i += 1024)
        atomicAdd(&dcnt[part[i] & 511], 1);
    __syncthreads();
    if (t < 512) sa[t] = dcnt[t];
    __syncthreads();
    for (int off = 1; off < 512; off <<= 1) {
        int v = 0;
        if (t < 512 && t >= off) v = sa[t - off];
        __syncthreads();
        if (t < 512) sa[t] += v;
        __syncthreads();
    }
    if (t < 512) {
        int excl = sa[t] - dcnt[t];
        curs[t] = e0 + excl;
        int node = b * 512 + t;
        if (node < N_NODES) row_start[node] = e0 + excl;
    }
    if (b == 0 && t == 0) row_start[N_NODES] = N_EDGES;
    __syncthreads();
    for (int i = e0 + t; i < e1; i += 1024) {
        unsigned int p = part[i];
        int pos = atomicAdd(&curs[p & 511], 1);  // LDS atomic
        csr_src[pos] = (int)(p >> 9);
    }
}

// --- gather-mean: 4 nodes/wave, 16 lanes/node, dense [N][128] src -> dense
// mean buffer. 16-deep clamped batch (P(deg<=16)=97%), 8/1 tails.
// Accepted at the chip's random-line service ceiling (r0/r4 evidence). ---
__global__ __launch_bounds__(256) void k_agg(
    const int* __restrict__ row_start, const int* __restrict__ csr_src,
    const unsigned short* __restrict__ src, unsigned short* __restrict__ mdst) {
    long long gt = (long long)blockIdx.x * blockDim.x + threadIdx.x;
    int node = (int)(gt >> 4);
    int lane = (int)(gt & 15);
    if (node >= N_NODES) return;
    int beg = row_start[node];
    int end = row_start[node + 1];
    int n = end - beg;
    float a[8];
#pragma unroll
    for (int j = 0; j < 8; j++) a[j] = 0.f;
    if (n > 0) {
        const unsigned short* gbase = src + lane * 8;
        int nm1 = n - 1;
        int s[16];
#pragma unroll
        for (int j = 0; j < 16; j++) {
            int jj = (j < nm1) ? j : nm1;          // clamp: always in [beg,end-1]
            s[j] = csr_src[beg + jj];
        }
        uint4 u[16];
#pragma unroll
        for (int j = 0; j < 16; j++)
            u[j] = *(const uint4*)(gbase + (size_t)s[j] * CH);
#pragma unroll
        for (int j = 0; j < 16; j++) {
            if (j < n) {                            // mask dup tail
                acc_u32(u[j].x, a[0], a[1]); acc_u32(u[j].y, a[2], a[3]);
                acc_u32(u[j].z, a[4], a[5]); acc_u32(u[j].w, a[6], a[7]);
            }
        }
        int e = beg + 16;
        while (e + 8 <= end) {
            int s2[8];
#pragma unroll
            for (int j = 0; j < 8; j++) s2[j] = csr_src[e + j];
            uint4 u2[8];
#pragma unroll
            for (int j = 0; j < 8; j++)
                u2[j] = *(const uint4*)(gbase + (size_t)s2[j] * CH);
#pragma unroll
            for (int j = 0; j < 8; j++) {
                acc_u32(u2[j].x, a[0], a[1]); acc_u32(u2[j].y, a[2], a[3]);
                acc_u32(u2[j].z, a[4], a[5]); acc_u32(u2[j].w, a[6], a[7]);
            }
            e += 8;
        }
        while (e < end) {
            int s0 = csr_src[e];
            uint4 u0 = *(const uint4*)(gbase + (size_t)s0 * CH);
            acc_u32(u0.x, a[0], a[1]); acc_u32(u0.y, a[2], a[3]);
            acc_u32(u0.z, a[4], a[5]); acc_u32(u0.w, a[6], a[7]);
            e++;
        }
    }
    float rinv = 1.0f / (float)max(n, 1);
    unsigned int p0 = (unsigned int)f2bf(a[0] * rinv) | ((unsigned int)f2bf(a[1] * rinv) << 16);
    unsigned int p1 = (unsigned int)f2bf(a[2] * rinv) | ((unsigned int)f2bf(a[3] * rinv) << 16);
    unsigned int p2 = (unsigned int)f2bf(a[4] * rinv) | ((unsigned int)f2bf(a[5] * rinv) << 16);
    unsigned int p3 = (unsigned int)f2bf(a[6] * rinv) | ((unsigned int)f2bf(a[7] * rinv) << 16);
    *(uint4*)(mdst + (size_t)node * CH + lane * 8) = make_uint4(p0, p1, p2, p3);
}

// --- MFMA GEMM (r5 restructure): B (64KB) resident in LDS once per block;
// A fragments loaded DIRECTLY global->reg (per-lane 16B, wave covers 16 rows
// x 2 full 128B lines -> coalesced at line granularity; x2 wave-level A
// re-read hits L2), software-prefetched 1 K-step ahead. ZERO main-loop
// barriers (was 16 full-drain barriers/block). LDB=264 halfwords = odd
// multiple of 16B (same conflict class as the proven LDK=40 layout). ---
#define LDB 264
#define CLS_LD 130
__global__ __launch_bounds__(256) void k_gemm_mfma(
    const unsigned short* __restrict__ Mb,     // [N][CH] mean, bf16
    const unsigned short* __restrict__ Xr,     // [N][CH] root, bf16
    const unsigned short* __restrict__ WT, const void* __restrict__ bias,
    const int* __restrict__ dtf,
    unsigned short* __restrict__ out,          // [N][CH] bf16 or null
    const void* __restrict__ wcls, const void* __restrict__ bcls,
    float* __restrict__ cls_out) {
    __shared__ unsigned short Bs[128 * LDB];   // 67,584 B
    const int t = threadIdx.x;
    const int w = t >> 6, l = t & 63;
    const int wx = w & 1, wy = w >> 1;
    const int quad = l >> 4, lrow = l & 15;
    const int row0 = blockIdx.x * 128;
    const int isbf = *dtf;

    {   // stage all of B: thread t copies row t>>1, half t&1 (16 x uint4)
        const int r = t >> 1, sh = t & 1;
        const unsigned short* bsrc = WT + (size_t)r * KTOT + sh * 128;
        unsigned short* bdst = Bs + r * LDB + sh * 128;
#pragma unroll
        for (int j = 0; j < 16; j++)
            *(uint4*)(bdst + j * 8) = *(const uint4*)(bsrc + j * 8);
    }

    const unsigned short* aM[4];
    const unsigned short* aX[4];
#pragma unroll
    for (int mi = 0; mi < 4; mi++) {
        int r = row0 + wy * 64 + mi * 16 + lrow;
        if (r >= N_NODES) r = N_NODES - 1;      // dup-load; stores guarded below
        aM[mi] = Mb + (size_t)r * CH + quad * 8;
        aX[mi] = Xr + (size_t)r * CH + quad * 8;
    }

    v4f acc[4][4];
#pragma unroll
    for (int i = 0; i < 4; i++)
#pragma unroll
        for (int j = 0; j < 4; j++) acc[i][j] = (v4f){0.f, 0.f, 0.f, 0.f};

    v8s afc[4];
#pragma unroll
    for (int mi = 0; mi < 4; mi++) afc[mi] = *(const v8s*)(aM[mi]);  // k=0

    __syncthreads();   // B ready; the ONLY barrier before the epilogue

#pragma unroll
    for (int k = 0; k < KTOT / 32; k++) {
        v8s afn[4];
        if (k < KTOT / 32 - 1) {
            const int kn = k + 1;
#pragma unroll
            for (int mi = 0; mi < 4; mi++)
                afn[mi] = *(const v8s*)((kn < 4) ? (aM[mi] + kn * 32)
                                                 : (aX[mi] + (kn - 4) * 32));
        }
        v8s bfr[4];
#pragma unroll
        for (int ni = 0; ni < 4; ni++)
            bfr[ni] = *(const v8s*)&Bs[(wx * 64 + ni * 16 + lrow) * LDB +
                                       k * 32 + quad * 8];
#pragma unroll
        for (int mi = 0; mi < 4; mi++)
#pragma unroll
            for (int ni = 0; ni < 4; ni++)
                acc[mi][ni] = __builtin_amdgcn_mfma_f32_16x16x32_bf16(
                    afc[mi], bfr[ni], acc[mi][ni], 0, 0, 0);
#pragma unroll
        for (int mi = 0; mi < 4; mi++) afc[mi] = afn[mi];
    }

    float bj[4];
#pragma unroll
    for (int ni = 0; ni < 4; ni++) bj[ni] = ldf(bias, isbf, wx * 64 + ni * 16 + lrow);

    if (!cls_out) {
#pragma unroll
        for (int mi = 0; mi < 4; mi++) {
#pragma unroll
            for (int r = 0; r < 4; r++) {
                int grow = row0 + wy * 64 + mi * 16 + quad * 4 + r;
                if (grow < N_NODES) {
#pragma unroll
                    for (int ni = 0; ni < 4; ni++) {
                        int col = wx * 64 + ni * 16 + lrow;
                        float v = fmaxf(acc[mi][ni][r] + bj[ni], 0.0f);
                        out[(size_t)grow * CH + col] = f2bf(v);
                    }
                }
            }
        }
    } else {
        __syncthreads();   // all waves done with Bs -> reuse as h-tile
        float* wcls_s = (float*)(Bs + 16896);  // 384 floats, fits in 67.6KB
        for (int i = t; i < CH * NCLS; i += 256) wcls_s[i] = ldf(wcls, isbf, i);
#pragma unroll
        for (int mi = 0; mi < 4; mi++) {
#pragma unroll
            for (int r = 0; r < 4; r++) {
                int row = wy * 64 + mi * 16 + quad * 4 + r;
#pragma unroll
                for (int ni = 0; ni < 4; ni++) {
                    int col = wx * 64 + ni * 16 + lrow;
                    float v = fmaxf(acc[mi][ni][r] + bj[ni], 0.0f);
                    Bs[row * CLS_LD + col] = f2bf(v);
                }
            }
        }
        __syncthreads();
        if (t < 128) {
            int grow = row0 + t;
            if (grow < N_NODES) {
                float a0 = 0.f, a1 = 0.f, a2 = 0.f;
                for (int k = 0; k < CH; k++) {
                    float h = bf2f(Bs[t * CLS_LD + k]);
                    a0 += h * wcls_s[k * NCLS + 0];
                    a1 += h * wcls_s[k * NCLS + 1];
                    a2 += h * wcls_s[k * NCLS + 2];
                }
                cls_out[(size_t)grow * NCLS + 0] = a0 + ldf(bcls, isbf, 0);
                cls_out[(size_t)grow * NCLS + 1] = a1 + ldf(bcls, isbf, 1);
                cls_out[(size_t)grow * NCLS + 2] = a2 + ldf(bcls, isbf, 2);
            }
        }
    }
}

extern "C" void kernel_launch(void* const* d_in, const int* in_sizes, int n_in,
                              void* d_out, int out_size, void* d_ws, size_t ws_size,
                              hipStream_t stream) {
    const void* x = d_in[0];
    const void* eidx = d_in[1];
    const void* w_l1 = d_in[2];
    const void* b_l1 = d_in[3];
    const void* w_r1 = d_in[4];
    const void* w_l2 = d_in[5];
    const void* b_l2 = d_in[6];
    const void* w_r2 = d_in[7];
    const void* w_cls = d_in[8];
    const void* b_cls = d_in[9];

    char* w = (char*)d_ws;
    int* eflag = (int*)w;
    int* dtf = (int*)(w + 64);
    int* done = (int*)(w + 128);
    int* hist = (int*)(w + 4096);                            // 192,080 B
    int* bsum = (int*)(w + 196608);                          // 188 B
    int* row_start = (int*)(w + 262144);                     // 400,004 B
    unsigned int* part = (unsigned int*)(w + 720896);        // 4 MB
    int* csr_src = (int*)(w + 4915200);                      // 4 MB
    unsigned short* WT1 = (unsigned short*)(w + 8978432);    // 64 KB
    unsigned short* WT2 = (unsigned short*)(w + 9043968);    // 64 KB
    unsigned short* Xb = (unsigned short*)(w + 11534336);    // 25.6 MB, ends 37,134,336
    unsigned short* Mb = (unsigned short*)(w + 37748736);    // 25.6 MB, ends 63,348,736
    unsigned short* Hb = (unsigned short*)(w + 67108864);    // 25.6 MB, ends 92,708,864

    hipLaunchKernelGGL(k_init, dim3(2), dim3(256), 0, stream,
                       eidx, (const unsigned int*)x, eflag, dtf, done);
    hipLaunchKernelGGL(k_A1, dim3(NB_A1), dim3(256), 0, stream,
                       eidx, eflag, dtf, hist, x, Xb,
                       w_l1, w_r1, WT1, w_l2, w_r2, WT2);
    hipLaunchKernelGGL(k_scanH, dim3(NB_SCAN), dim3(1024), 0, stream,
                       hist, bsum, done);
    hipLaunchKernelGGL(k_A3, dim3(NB_A), dim3(256), 0, stream,
                       eidx, eflag, hist, part);
    hipLaunchKernelGGL(k_B, dim3(NBKT), dim3(1024), 0, stream,
                       hist, part, row_start, csr_src);
    // layer 1: gather Xb -> Mb, then GEMM (Mb ++ Xb) -> Hb
    hipLaunchKernelGGL(k_agg, dim3(N_NODES * 16 / 256), dim3(256), 0, stream,
                       row_start, csr_src, Xb, Mb);
    hipLaunchKernelGGL(k_gemm_mfma, dim3((N_NODES + 127) / 128), dim3(256), 0, stream,
                       Mb, Xb, WT1, b_l1, dtf, Hb,
                       (const void*)nullptr, (const void*)nullptr, (float*)nullptr);
    // layer 2: gather Hb -> Mb, then GEMM (Mb ++ Hb) + classifier -> logits
    hipLaunchKernelGGL(k_agg, dim3(N_NODES * 16 / 256), dim3(256), 0, stream,
                       row_start, csr_src, Hb, Mb);
    hipLaunchKernelGGL(k_gemm_mfma, dim3((N_NODES + 127) / 128), dim3(256), 0, stream,
                       Mb, Hb, WT2, b_l2, dtf, (unsigned short*)nullptr,
                       w_cls, b_cls, (float*)d_out);
}

// Round 6
// 271.255 us; speedup vs baseline: 1.0302x; 1.0302x over previous
//
#include <hip/hip_runtime.h>
#include <hip/hip_bf16.h>

#define N_NODES 100000
#define N_EDGES 1000000
#define CH 128
#define KTOT 256
#define NCLS 3

#define NBKT 196                    // coarse buckets: dst>>9
#define EPB 4096                    // edges per partition block (parallelism!)
#define NB_A ((N_EDGES + EPB - 1) / EPB)          // 245
#define M_H (NBKT * NB_A)                          // 48020
#define NB_SCAN ((M_H + 1023) / 1024)              // 47 co-resident blocks

#define NB_CVTX (N_NODES * CH / 4 / 256)           // 12500
#define NB_CVTW (KTOT * CH / 256)                  // 128
#define NB_A1 (NB_A + NB_CVTX + 2 * NB_CVTW)       // 13001

typedef __attribute__((ext_vector_type(8))) short v8s;   // 8 bf16 (A/B frag)
typedef __attribute__((ext_vector_type(4))) float v4f;   // 4 f32 (C/D frag)

__device__ __forceinline__ float bf2f(unsigned short u) {
    return __uint_as_float(((unsigned int)u) << 16);
}

__device__ __forceinline__ unsigned short f2bf(float f) {  // RNE
    unsigned int u = __float_as_uint(f);
    unsigned int r = (u + 0x7fffu + ((u >> 16) & 1u)) >> 16;
    return (unsigned short)r;
}

__device__ __forceinline__ int edge_at(const void* e, int is64, long long i) {
    if (is64) return (int)((const long long*)e)[i];
    return ((const int*)e)[i];
}

__device__ __forceinline__ float ldf(const void* p, int isbf, size_t i) {
    if (isbf) return bf2f(((const unsigned short*)p)[i]);
    return ((const float*)p)[i];
}

__device__ __forceinline__ void acc_u32(unsigned int u, float& a0, float& a1) {
    a0 += bf2f((unsigned short)(u & 0xffffu));
    a1 += bf2f((unsigned short)(u >> 16));
}

// --- K0: dtype sniffers + done flag ---
__global__ void k_init(const void* __restrict__ e, const unsigned int* __restrict__ x,
                       int* __restrict__ eflag, int* __restrict__ dtf,
                       int* __restrict__ done) {
    if (blockIdx.x == 0) {
        if (threadIdx.x < 64) {
            int v = ((const int*)e)[2 * threadIdx.x + 1];
            unsigned long long bl = __ballot(v != 0);
            if (threadIdx.x == 0) *eflag = (bl == 0ULL) ? 1 : 0;
        } else if (threadIdx.x == 64) {
            *done = 0;
        }
    } else {
        if (threadIdx.x < 64) {
            unsigned int u = x[threadIdx.x];
            int ex = (u >> 7) & 0xff;
            int sane = (ex == 0) || (ex >= 100 && ex <= 154);
            unsigned long long bl = __ballot(sane);
            if (threadIdx.x == 0) *dtf = (__popcll(bl) >= 48) ? 1 : 0;
        }
    }
}

// --- K1: coarse-bucket histogram (LDS atomics only) interleaved with cvt.
// x converts to a DENSE [N][128] bf16 buffer. ---
__global__ void k_A1(const void* __restrict__ e, const int* __restrict__ eflag,
                     const int* __restrict__ dtf, int* __restrict__ hist,
                     const void* __restrict__ x, unsigned short* __restrict__ Xb,
                     const void* __restrict__ wl1, const void* __restrict__ wr1,
                     unsigned short* __restrict__ WT1,
                     const void* __restrict__ wl2, const void* __restrict__ wr2,
                     unsigned short* __restrict__ WT2) {
    int b = blockIdx.x;
    int t = threadIdx.x;
    if (b < NB_A) {
        __shared__ int h[NBKT];
        if (t < NBKT) h[t] = 0;
        __syncthreads();
        int is64 = *eflag;
#pragma unroll
        for (int j = 0; j < EPB / 256; j++) {
            int i = b * EPB + j * 256 + t;
            if (i < N_EDGES) {
                int dst = edge_at(e, is64, (long long)N_EDGES + i);
                atomicAdd(&h[dst >> 9], 1);
            }
        }
        __syncthreads();
        if (t < NBKT) hist[t * NB_A + b] = h[t];
    } else {
        int ob = b - NB_A;
        if (ob < NB_CVTX) {
            int idx = ob * 256 + t;
            int node = idx >> 5;
            int ch = (idx & 31) * 4;
            int isbf = *dtf;
            unsigned short o[4];
            if (isbf) {
                ushort4 u = *(const ushort4*)((const unsigned short*)x +
                                              (size_t)node * CH + ch);
                o[0] = u.x; o[1] = u.y; o[2] = u.z; o[3] = u.w;
            } else {
                float4 v = *(const float4*)((const float*)x + (size_t)node * CH + ch);
                o[0] = f2bf(v.x); o[1] = f2bf(v.y); o[2] = f2bf(v.z); o[3] = f2bf(v.w);
            }
            *(ushort4*)(Xb + (size_t)node * CH + ch) =
                make_ushort4(o[0], o[1], o[2], o[3]);
        } else {
            int rel = ob - NB_CVTX;
            const void* wl = (rel < NB_CVTW) ? wl1 : wl2;
            const void* wr = (rel < NB_CVTW) ? wr1 : wr2;
            unsigned short* WT = (rel < NB_CVTW) ? WT1 : WT2;
            int i = (rel % NB_CVTW) * 256 + t;
            int k = i >> 7;
            int n = i & 127;
            int isbf = *dtf;
            float v = (k < CH) ? ldf(wl, isbf, (size_t)k * CH + n)
                               : ldf(wr, isbf, (size_t)(k - CH) * CH + n);
            WT[(size_t)n * KTOT + k] = f2bf(v);
        }
    }
}

// --- K2: multi-block exclusive scan, producer-only spin barrier ---
__global__ __launch_bounds__(1024) void k_scanH(int* __restrict__ hist,
                                                int* __restrict__ bsum,
                                                int* __restrict__ done) {
    __shared__ int s[1024];
    __shared__ int pre_sh;
    int t = threadIdx.x, b = blockIdx.x;
    int idx = b * 1024 + t;
    int v = (idx < M_H) ? hist[idx] : 0;
    s[t] = v;
    __syncthreads();
    for (int off = 1; off < 1024; off <<= 1) {
        int u = (t >= off) ? s[t - off] : 0;
        __syncthreads();
        s[t] += u;
        __syncthreads();
    }
    if (t == 1023) {
        bsum[b] = s[t];
        __threadfence();
        atomicAdd(done, 1);
    }
    if (t == 0) {
        while (__hip_atomic_load(done, __ATOMIC_ACQUIRE,
                                 __HIP_MEMORY_SCOPE_AGENT) < NB_SCAN) {
        }
        __threadfence();
        int run = 0;
        for (int r = 0; r < b; r++) run += bsum[r];
        pre_sh = run;
    }
    __syncthreads();
    if (idx < M_H) hist[idx] = s[t] - v + pre_sh;  // exclusive
}

// --- K3: partition scatter via LDS cursors; pack (src<<9)|(dst&511) ---
__global__ void k_A3(const void* __restrict__ e, const int* __restrict__ eflag,
                     const int* __restrict__ hist, unsigned int* __restrict__ part) {
    __shared__ int cur[NBKT];
    int b = blockIdx.x;
    int t = threadIdx.x;
    if (t < NBKT) cur[t] = hist[t * NB_A + b];
    __syncthreads();
    int is64 = *eflag;
#pragma unroll
    for (int j = 0; j < EPB / 256; j++) {
        int i = b * EPB + j * 256 + t;
        if (i < N_EDGES) {
            int src = edge_at(e, is64, i);
            int dst = edge_at(e, is64, (long long)N_EDGES + i);
            int pos = atomicAdd(&cur[dst >> 9], 1);  // LDS atomic
            part[pos] = ((unsigned int)src << 9) | (unsigned int)(dst & 511);
        }
    }
}

// --- K4: per-bucket finalize: degree count + scan -> row_start + csr_src ---
__global__ __launch_bounds__(1024) void k_B(const int* __restrict__ hist,
                                            const unsigned int* __restrict__ part,
                                            int* __restrict__ row_start,
                                            int* __restrict__ csr_src) {
    __shared__ int dcnt[512], sa[512], curs[512];
    int b = blockIdx.x;
    int t = threadIdx.x;
    int e0 = hist[b * NB_A];
    int e1 = (b + 1 < NBKT) ? hist[(b + 1) * NB_A] : N_EDGES;
    if (t < 512) dcnt[t] = 0;
    __syncthreads();
    for (int i = e0 + t; i < e1; i += 1024)
        atomicAdd(&dcnt[part[i] & 511], 1);
    __syncthreads();
    if (t < 512) sa[t] = dcnt[t];
    __syncthreads();
    for (int off = 1; off < 512; off <<= 1) {
        int v = 0;
        if (t < 512 && t >= off) v = sa[t - off];
        __syncthreads();
        if (t < 512) sa[t] += v;
        __syncthreads();
    }
    if (t < 512) {
        int excl = sa[t] - dcnt[t];
        curs[t] = e0 + excl;
        int node = b * 512 + t;
        if (node < N_NODES) row_start[node] = e0 + excl;
    }
    if (b == 0 && t == 0) row_start[N_NODES] = N_EDGES;
    __syncthreads();
    for (int i = e0 + t; i < e1; i += 1024) {
        unsigned int p = part[i];
        int pos = atomicAdd(&curs[p & 511], 1);  // LDS atomic
        csr_src[pos] = (int)(p >> 9);
    }
}

// --- gather-mean: 4 nodes/wave, 16 lanes/node, dense [N][128] src -> dense
// mean buffer. 16-deep clamped batch (P(deg<=16)=97%), 8/1 tails.
// Accepted at the chip's random-line service ceiling (r0/r4 evidence). ---
__global__ __launch_bounds__(256) void k_agg(
    const int* __restrict__ row_start, const int* __restrict__ csr_src,
    const unsigned short* __restrict__ src, unsigned short* __restrict__ mdst) {
    long long gt = (long long)blockIdx.x * blockDim.x + threadIdx.x;
    int node = (int)(gt >> 4);
    int lane = (int)(gt & 15);
    if (node >= N_NODES) return;
    int beg = row_start[node];
    int end = row_start[node + 1];
    int n = end - beg;
    float a[8];
#pragma unroll
    for (int j = 0; j < 8; j++) a[j] = 0.f;
    if (n > 0) {
        const unsigned short* gbase = src + lane * 8;
        int nm1 = n - 1;
        int s[16];
#pragma unroll
        for (int j = 0; j < 16; j++) {
            int jj = (j < nm1) ? j : nm1;          // clamp: always in [beg,end-1]
            s[j] = csr_src[beg + jj];
        }
        uint4 u[16];
#pragma unroll
        for (int j = 0; j < 16; j++)
            u[j] = *(const uint4*)(gbase + (size_t)s[j] * CH);
#pragma unroll
        for (int j = 0; j < 16; j++) {
            if (j < n) {                            // mask dup tail
                acc_u32(u[j].x, a[0], a[1]); acc_u32(u[j].y, a[2], a[3]);
                acc_u32(u[j].z, a[4], a[5]); acc_u32(u[j].w, a[6], a[7]);
            }
        }
        int e = beg + 16;
        while (e + 8 <= end) {
            int s2[8];
#pragma unroll
            for (int j = 0; j < 8; j++) s2[j] = csr_src[e + j];
            uint4 u2[8];
#pragma unroll
            for (int j = 0; j < 8; j++)
                u2[j] = *(const uint4*)(gbase + (size_t)s2[j] * CH);
#pragma unroll
            for (int j = 0; j < 8; j++) {
                acc_u32(u2[j].x, a[0], a[1]); acc_u32(u2[j].y, a[2], a[3]);
                acc_u32(u2[j].z, a[4], a[5]); acc_u32(u2[j].w, a[6], a[7]);
            }
            e += 8;
        }
        while (e < end) {
            int s0 = csr_src[e];
            uint4 u0 = *(const uint4*)(gbase + (size_t)s0 * CH);
            acc_u32(u0.x, a[0], a[1]); acc_u32(u0.y, a[2], a[3]);
            acc_u32(u0.z, a[4], a[5]); acc_u32(u0.w, a[6], a[7]);
            e++;
        }
    }
    float rinv = 1.0f / (float)max(n, 1);
    unsigned int p0 = (unsigned int)f2bf(a[0] * rinv) | ((unsigned int)f2bf(a[1] * rinv) << 16);
    unsigned int p1 = (unsigned int)f2bf(a[2] * rinv) | ((unsigned int)f2bf(a[3] * rinv) << 16);
    unsigned int p2 = (unsigned int)f2bf(a[4] * rinv) | ((unsigned int)f2bf(a[5] * rinv) << 16);
    unsigned int p3 = (unsigned int)f2bf(a[6] * rinv) | ((unsigned int)f2bf(a[7] * rinv) << 16);
    *(uint4*)(mdst + (size_t)node * CH + lane * 8) = make_uint4(p0, p1, p2, p3);
}

// --- MFMA GEMM (r6): B double-buffered in LDS per K-step (r4's proven LDK=40
// layout + 1 barrier/step), A streamed DIRECTLY global->reg with 1-step
// prefetch (kills the A LDS round-trip of r4). LDS sized 36.9KB (cls tile
// needs 34.8KB) -> 4 blocks/CU by LDS, fixing r5's 67.6KB/2-blocks bug. ---
#define LDK 40
#define CLS_LD 130
#define SMEM_H 18432   // halfwords = 36,864 B >= max(2*128*LDK=10240hw, cls 17408hw)
__global__ __launch_bounds__(256) void k_gemm_mfma(
    const unsigned short* __restrict__ Mb,     // [N][CH] mean, bf16
    const unsigned short* __restrict__ Xr,     // [N][CH] root, bf16
    const unsigned short* __restrict__ WT, const void* __restrict__ bias,
    const int* __restrict__ dtf,
    unsigned short* __restrict__ out,          // [N][CH] bf16 or null
    const void* __restrict__ wcls, const void* __restrict__ bcls,
    float* __restrict__ cls_out) {
    __shared__ unsigned short smem[SMEM_H];
    unsigned short* Bs = smem;                 // dbuf: [0] and [128*LDK]
    const int t = threadIdx.x;
    const int w = t >> 6, l = t & 63;
    const int wx = w & 1, wy = w >> 1;
    const int quad = l >> 4, lrow = l & 15;
    const int row0 = blockIdx.x * 128;
    const int srow = t >> 1, shalf = t & 1;
    const int isbf = *dtf;

    const unsigned short* bbase = WT + (size_t)srow * KTOT + shalf * 16;

    // A fragment pointers: per mi, this lane's row (clamped; stores guarded)
    const unsigned short* aM[4];
    const unsigned short* aX[4];
#pragma unroll
    for (int mi = 0; mi < 4; mi++) {
        int r = row0 + wy * 64 + mi * 16 + lrow;
        if (r >= N_NODES) r = N_NODES - 1;
        aM[mi] = Mb + (size_t)r * CH + quad * 8;
        aX[mi] = Xr + (size_t)r * CH + quad * 8;
    }

    v4f acc[4][4];
#pragma unroll
    for (int i = 0; i < 4; i++)
#pragma unroll
        for (int j = 0; j < 4; j++) acc[i][j] = (v4f){0.f, 0.f, 0.f, 0.f};

    v8s afc[4];
#pragma unroll
    for (int mi = 0; mi < 4; mi++) afc[mi] = *(const v8s*)(aM[mi]);  // k=0

    {   // prologue: stage B step 0 into buffer 0
        uint4 b0 = *(const uint4*)bbase, b1 = *(const uint4*)(bbase + 8);
        *(uint4*)&Bs[srow * LDK + shalf * 16] = b0;
        *(uint4*)&Bs[srow * LDK + shalf * 16 + 8] = b1;
    }
#pragma unroll
    for (int k = 0; k < KTOT / 32; k++) {
        uint4 nb0, nb1;
        v8s afn[4];
        if (k < KTOT / 32 - 1) {
            const int kn = k + 1;
            nb0 = *(const uint4*)(bbase + kn * 32);
            nb1 = *(const uint4*)(bbase + kn * 32 + 8);
#pragma unroll
            for (int mi = 0; mi < 4; mi++)
                afn[mi] = *(const v8s*)((kn < 4) ? (aM[mi] + kn * 32)
                                                 : (aX[mi] + (kn - 4) * 32));
        }
        __syncthreads();
        const int cur = (k & 1) * 128 * LDK, nxt = ((k + 1) & 1) * 128 * LDK;
        v8s bfr[4];
#pragma unroll
        for (int ni = 0; ni < 4; ni++)
            bfr[ni] = *(const v8s*)&Bs[cur + (wx * 64 + ni * 16 + lrow) * LDK + quad * 8];
#pragma unroll
        for (int mi = 0; mi < 4; mi++)
#pragma unroll
            for (int ni = 0; ni < 4; ni++)
                acc[mi][ni] = __builtin_amdgcn_mfma_f32_16x16x32_bf16(
                    afc[mi], bfr[ni], acc[mi][ni], 0, 0, 0);
        if (k < KTOT / 32 - 1) {
            *(uint4*)&Bs[nxt + srow * LDK + shalf * 16] = nb0;
            *(uint4*)&Bs[nxt + srow * LDK + shalf * 16 + 8] = nb1;
#pragma unroll
            for (int mi = 0; mi < 4; mi++) afc[mi] = afn[mi];
        }
    }
    float bj[4];
#pragma unroll
    for (int ni = 0; ni < 4; ni++) bj[ni] = ldf(bias, isbf, wx * 64 + ni * 16 + lrow);

    if (!cls_out) {
#pragma unroll
        for (int mi = 0; mi < 4; mi++) {
#pragma unroll
            for (int r = 0; r < 4; r++) {
                int grow = row0 + wy * 64 + mi * 16 + quad * 4 + r;
                if (grow < N_NODES) {
#pragma unroll
                    for (int ni = 0; ni < 4; ni++) {
                        int col = wx * 64 + ni * 16 + lrow;
                        float v = fmaxf(acc[mi][ni][r] + bj[ni], 0.0f);
                        out[(size_t)grow * CH + col] = f2bf(v);
                    }
                }
            }
        }
    } else {
        __syncthreads();   // all waves done with Bs -> reuse smem as h-tile
        float* wcls_s = (float*)(smem + 16640);  // tile ends at hw 16640; +1536B fits
        for (int i = t; i < CH * NCLS; i += 256) wcls_s[i] = ldf(wcls, isbf, i);
#pragma unroll
        for (int mi = 0; mi < 4; mi++) {
#pragma unroll
            for (int r = 0; r < 4; r++) {
                int row = wy * 64 + mi * 16 + quad * 4 + r;
#pragma unroll
                for (int ni = 0; ni < 4; ni++) {
                    int col = wx * 64 + ni * 16 + lrow;
                    float v = fmaxf(acc[mi][ni][r] + bj[ni], 0.0f);
                    smem[row * CLS_LD + col] = f2bf(v);
                }
            }
        }
        __syncthreads();
        if (t < 128) {
            int grow = row0 + t;
            if (grow < N_NODES) {
                float a0 = 0.f, a1 = 0.f, a2 = 0.f;
                for (int k = 0; k < CH; k++) {
                    float h = bf2f(smem[t * CLS_LD + k]);
                    a0 += h * wcls_s[k * NCLS + 0];
                    a1 += h * wcls_s[k * NCLS + 1];
                    a2 += h * wcls_s[k * NCLS + 2];
                }
                cls_out[(size_t)grow * NCLS + 0] = a0 + ldf(bcls, isbf, 0);
                cls_out[(size_t)grow * NCLS + 1] = a1 + ldf(bcls, isbf, 1);
                cls_out[(size_t)grow * NCLS + 2] = a2 + ldf(bcls, isbf, 2);
            }
        }
    }
}

extern "C" void kernel_launch(void* const* d_in, const int* in_sizes, int n_in,
                              void* d_out, int out_size, void* d_ws, size_t ws_size,
                              hipStream_t stream) {
    const void* x = d_in[0];
    const void* eidx = d_in[1];
    const void* w_l1 = d_in[2];
    const void* b_l1 = d_in[3];
    const void* w_r1 = d_in[4];
    const void* w_l2 = d_in[5];
    const void* b_l2 = d_in[6];
    const void* w_r2 = d_in[7];
    const void* w_cls = d_in[8];
    const void* b_cls = d_in[9];

    char* w = (char*)d_ws;
    int* eflag = (int*)w;
    int* dtf = (int*)(w + 64);
    int* done = (int*)(w + 128);
    int* hist = (int*)(w + 4096);                            // 192,080 B
    int* bsum = (int*)(w + 196608);                          // 188 B
    int* row_start = (int*)(w + 262144);                     // 400,004 B
    unsigned int* part = (unsigned int*)(w + 720896);        // 4 MB
    int* csr_src = (int*)(w + 4915200);                      // 4 MB
    unsigned short* WT1 = (unsigned short*)(w + 8978432);    // 64 KB
    unsigned short* WT2 = (unsigned short*)(w + 9043968);    // 64 KB
    unsigned short* Xb = (unsigned short*)(w + 11534336);    // 25.6 MB, ends 37,134,336
    unsigned short* Mb = (unsigned short*)(w + 37748736);    // 25.6 MB, ends 63,348,736
    unsigned short* Hb = (unsigned short*)(w + 67108864);    // 25.6 MB, ends 92,708,864

    hipLaunchKernelGGL(k_init, dim3(2), dim3(256), 0, stream,
                       eidx, (const unsigned int*)x, eflag, dtf, done);
    hipLaunchKernelGGL(k_A1, dim3(NB_A1), dim3(256), 0, stream,
                       eidx, eflag, dtf, hist, x, Xb,
                       w_l1, w_r1, WT1, w_l2, w_r2, WT2);
    hipLaunchKernelGGL(k_scanH, dim3(NB_SCAN), dim3(1024), 0, stream,
                       hist, bsum, done);
    hipLaunchKernelGGL(k_A3, dim3(NB_A), dim3(256), 0, stream,
                       eidx, eflag, hist, part);
    hipLaunchKernelGGL(k_B, dim3(NBKT), dim3(1024), 0, stream,
                       hist, part, row_start, csr_src);
    // layer 1: gather Xb -> Mb, then GEMM (Mb ++ Xb) -> Hb
    hipLaunchKernelGGL(k_agg, dim3(N_NODES * 16 / 256), dim3(256), 0, stream,
                       row_start, csr_src, Xb, Mb);
    hipLaunchKernelGGL(k_gemm_mfma, dim3((N_NODES + 127) / 128), dim3(256), 0, stream,
                       Mb, Xb, WT1, b_l1, dtf, Hb,
                       (const void*)nullptr, (const void*)nullptr, (float*)nullptr);
    // layer 2: gather Hb -> Mb, then GEMM (Mb ++ Hb) + classifier -> logits
    hipLaunchKernelGGL(k_agg, dim3(N_NODES * 16 / 256), dim3(256), 0, stream,
                       row_start, csr_src, Hb, Mb);
    hipLaunchKernelGGL(k_gemm_mfma, dim3((N_NODES + 127) / 128), dim3(256), 0, stream,
                       Mb, Hb, WT2, b_l2, dtf, (unsigned short*)nullptr,
                       w_cls, b_cls, (float*)d_out);
}

// Round 7
// 256.129 us; speedup vs baseline: 1.0910x; 1.0591x over previous
//
#include <hip/hip_runtime.h>
#include <hip/hip_bf16.h>

#define N_NODES 100000
#define N_EDGES 1000000
#define CH 128
#define KTOT 256
#define NCLS 3

#define NBKT 196                    // coarse buckets: dst>>9
#define EPB 4096                    // edges per partition block (parallelism!)
#define NB_A ((N_EDGES + EPB - 1) / EPB)          // 245
#define M_H (NBKT * NB_A)                          // 48020
#define NB_SCAN ((M_H + 1023) / 1024)              // 47 co-resident blocks

#define NB_CVTX (N_NODES * CH / 4 / 256)           // 12500 x-cvt tiles (256 thr each)
#define NB_CVTW (KTOT * CH / 256)                  // 128 WT tiles per layer
// x-cvt tile distribution across the CSR chain (fills idle CUs):
#define CVT_SCAN 4000                              // tiles [0,4000) in k_scanH
#define CVT_A3   4500                              // tiles [4000,8500) in k_A3
#define CVT_B    4000                              // tiles [8500,12500) in k_B

typedef __attribute__((ext_vector_type(8))) short v8s;   // 8 bf16 (A/B frag)
typedef __attribute__((ext_vector_type(4))) float v4f;   // 4 f32 (C/D frag)

__device__ __forceinline__ float bf2f(unsigned short u) {
    return __uint_as_float(((unsigned int)u) << 16);
}

__device__ __forceinline__ unsigned short f2bf(float f) {  // RNE
    unsigned int u = __float_as_uint(f);
    unsigned int r = (u + 0x7fffu + ((u >> 16) & 1u)) >> 16;
    return (unsigned short)r;
}

__device__ __forceinline__ int edge_at(const void* e, int is64, long long i) {
    if (is64) return (int)((const long long*)e)[i];
    return ((const int*)e)[i];
}

__device__ __forceinline__ float ldf(const void* p, int isbf, size_t i) {
    if (isbf) return bf2f(((const unsigned short*)p)[i]);
    return ((const float*)p)[i];
}

__device__ __forceinline__ void acc_u32(unsigned int u, float& a0, float& a1) {
    a0 += bf2f((unsigned short)(u & 0xffffu));
    a1 += bf2f((unsigned short)(u >> 16));
}

// wave-level dtype sniffs (deterministic: every wave computes the same value)
__device__ __forceinline__ int sniff_is64(const void* e) {
    int lane = threadIdx.x & 63;
    int v = ((const int*)e)[2 * lane + 1];
    unsigned long long bl = __ballot(v != 0);
    return (bl == 0ULL) ? 1 : 0;
}

__device__ __forceinline__ int sniff_isbf(const void* x) {
    int lane = threadIdx.x & 63;
    unsigned int u = ((const unsigned int*)x)[lane];
    int ex = (u >> 7) & 0xff;
    int sane = (ex == 0) || (ex >= 100 && ex <= 154);
    unsigned long long bl = __ballot(sane);
    return (__popcll(bl) >= 48) ? 1 : 0;
}

// one x-cvt tile: 256 work units = 8 nodes x 32 ch4-groups
__device__ __forceinline__ void cvt_x_tile(int tile, int t256, const void* x,
                                           unsigned short* Xb, int isbf) {
    int idx = tile * 256 + t256;
    int node = idx >> 5;
    int ch = (idx & 31) * 4;
    unsigned short o[4];
    if (isbf) {
        ushort4 u = *(const ushort4*)((const unsigned short*)x +
                                      (size_t)node * CH + ch);
        o[0] = u.x; o[1] = u.y; o[2] = u.z; o[3] = u.w;
    } else {
        float4 v = *(const float4*)((const float*)x + (size_t)node * CH + ch);
        o[0] = f2bf(v.x); o[1] = f2bf(v.y); o[2] = f2bf(v.z); o[3] = f2bf(v.w);
    }
    *(ushort4*)(Xb + (size_t)node * CH + ch) = make_ushort4(o[0], o[1], o[2], o[3]);
}

// --- K1: coarse-bucket histogram (self-sniffed dtypes; block 0 publishes
// eflag/dtf/done for later kernels) + WT cvt tiles. x-cvt moved out (r7)
// to overlap with the CSR chain. ---
__global__ void k_A1(const void* __restrict__ e, int* __restrict__ eflag,
                     int* __restrict__ dtf, int* __restrict__ done,
                     int* __restrict__ hist,
                     const void* __restrict__ x,
                     const void* __restrict__ wl1, const void* __restrict__ wr1,
                     unsigned short* __restrict__ WT1,
                     const void* __restrict__ wl2, const void* __restrict__ wr2,
                     unsigned short* __restrict__ WT2) {
    int b = blockIdx.x;
    int t = threadIdx.x;
    if (b < NB_A) {
        __shared__ int h[NBKT];
        if (t < NBKT) h[t] = 0;
        int is64 = sniff_is64(e);          // per-wave, uniform
        if (b == 0 && t < 64) {            // publish for later kernels
            int isbf = sniff_isbf(x);
            if (t == 0) { *eflag = is64; *dtf = isbf; *done = 0; }
        }
        __syncthreads();
#pragma unroll
        for (int j = 0; j < EPB / 256; j++) {
            int i = b * EPB + j * 256 + t;
            if (i < N_EDGES) {
                int dst = edge_at(e, is64, (long long)N_EDGES + i);
                atomicAdd(&h[dst >> 9], 1);
            }
        }
        __syncthreads();
        if (t < NBKT) hist[t * NB_A + b] = h[t];
    } else {
        int rel = b - NB_A;                // [0, 2*NB_CVTW): WT cvt
        int isbf = sniff_isbf(x);
        const void* wl = (rel < NB_CVTW) ? wl1 : wl2;
        const void* wr = (rel < NB_CVTW) ? wr1 : wr2;
        unsigned short* WT = (rel < NB_CVTW) ? WT1 : WT2;
        int i = (rel % NB_CVTW) * 256 + t;
        int k = i >> 7;
        int n = i & 127;
        float v = (k < CH) ? ldf(wl, isbf, (size_t)k * CH + n)
                           : ldf(wr, isbf, (size_t)(k - CH) * CH + n);
        WT[(size_t)n * KTOT + k] = f2bf(v);
    }
}

// --- K2: multi-block exclusive scan (producer-only spin; the 47 scan blocks
// are dispatched first and are the only spinners) + x-cvt tail blocks ---
__global__ __launch_bounds__(1024) void k_scanH(int* __restrict__ hist,
                                                int* __restrict__ bsum,
                                                int* __restrict__ done,
                                                const void* __restrict__ x,
                                                unsigned short* __restrict__ Xb,
                                                const int* __restrict__ dtf) {
    __shared__ int s[1024];
    __shared__ int pre_sh;
    int t = threadIdx.x, b = blockIdx.x;
    if (b >= NB_SCAN) {                    // x-cvt: 4 tiles per 1024-thr block
        int cb = b - NB_SCAN;
        int isbf = *dtf;
        cvt_x_tile(cb * 4 + (t >> 8), t & 255, x, Xb, isbf);
        return;
    }
    int idx = b * 1024 + t;
    int v = (idx < M_H) ? hist[idx] : 0;
    s[t] = v;
    __syncthreads();
    for (int off = 1; off < 1024; off <<= 1) {
        int u = (t >= off) ? s[t - off] : 0;
        __syncthreads();
        s[t] += u;
        __syncthreads();
    }
    if (t == 1023) {
        bsum[b] = s[t];
        __threadfence();
        atomicAdd(done, 1);
    }
    if (t == 0) {
        while (__hip_atomic_load(done, __ATOMIC_ACQUIRE,
                                 __HIP_MEMORY_SCOPE_AGENT) < NB_SCAN) {
        }
        __threadfence();
        int run = 0;
        for (int r = 0; r < b; r++) run += bsum[r];
        pre_sh = run;
    }
    __syncthreads();
    if (idx < M_H) hist[idx] = s[t] - v + pre_sh;  // exclusive
}

// --- K3: partition scatter via LDS cursors + x-cvt tail blocks ---
__global__ void k_A3(const void* __restrict__ e, const int* __restrict__ eflag,
                     const int* __restrict__ hist, unsigned int* __restrict__ part,
                     const void* __restrict__ x, unsigned short* __restrict__ Xb,
                     const int* __restrict__ dtf) {
    __shared__ int cur[NBKT];
    int b = blockIdx.x;
    int t = threadIdx.x;
    if (b >= NB_A) {                       // x-cvt: 1 tile per 256-thr block
        int isbf = *dtf;
        cvt_x_tile(CVT_SCAN + (b - NB_A), t, x, Xb, isbf);
        return;
    }
    if (t < NBKT) cur[t] = hist[t * NB_A + b];
    __syncthreads();
    int is64 = *eflag;
#pragma unroll
    for (int j = 0; j < EPB / 256; j++) {
        int i = b * EPB + j * 256 + t;
        if (i < N_EDGES) {
            int src = edge_at(e, is64, i);
            int dst = edge_at(e, is64, (long long)N_EDGES + i);
            int pos = atomicAdd(&cur[dst >> 9], 1);  // LDS atomic
            part[pos] = ((unsigned int)src << 9) | (unsigned int)(dst & 511);
        }
    }
}

// --- K4: per-bucket finalize + x-cvt tail blocks ---
__global__ __launch_bounds__(1024) void k_B(const int* __restrict__ hist,
                                            const unsigned int* __restrict__ part,
                                            int* __restrict__ row_start,
                                            int* __restrict__ csr_src,
                                            const void* __restrict__ x,
                                            unsigned short* __restrict__ Xb,
                                            const int* __restrict__ dtf) {
    __shared__ int dcnt[512], sa[512], curs[512];
    int b = blockIdx.x;
    int t = threadIdx.x;
    if (b >= NBKT) {                       // x-cvt: 4 tiles per 1024-thr block
        int cb = b - NBKT;
        int isbf = *dtf;
        cvt_x_tile(CVT_SCAN + CVT_A3 + cb * 4 + (t >> 8), t & 255, x, Xb, isbf);
        return;
    }
    int e0 = hist[b * NB_A];
    int e1 = (b + 1 < NBKT) ? hist[(b + 1) * NB_A] : N_EDGES;
    if (t < 512) dcnt[t] = 0;
    __syncthreads();
    for (int i = e0 + t; i < e1; i += 1024)
        atomicAdd(&dcnt[part[i] & 511], 1);
    __syncthreads();
    if (t < 512) sa[t] = dcnt[t];
    __syncthreads();
    for (int off = 1; off < 512; off <<= 1) {
        int v = 0;
        if (t < 512 && t >= off) v = sa[t - off];
        __syncthreads();
        if (t < 512) sa[t] += v;
        __syncthreads();
    }
    if (t < 512) {
        int excl = sa[t] - dcnt[t];
        curs[t] = e0 + excl;
        int node = b * 512 + t;
        if (node < N_NODES) row_start[node] = e0 + excl;
    }
    if (b == 0 && t == 0) row_start[N_NODES] = N_EDGES;
    __syncthreads();
    for (int i = e0 + t; i < e1; i += 1024) {
        unsigned int p = part[i];
        int pos = atomicAdd(&curs[p & 511], 1);  // LDS atomic
        csr_src[pos] = (int)(p >> 9);
    }
}

// --- gather-mean: 4 nodes/wave, 16 lanes/node, dense [N][128] src -> dense
// mean buffer. 16-deep clamped batch (P(deg<=16)=97%), 8/1 tails.
// Accepted at the chip's random-line service ceiling (r0/r4 evidence). ---
__global__ __launch_bounds__(256) void k_agg(
    const int* __restrict__ row_start, const int* __restrict__ csr_src,
    const unsigned short* __restrict__ src, unsigned short* __restrict__ mdst) {
    long long gt = (long long)blockIdx.x * blockDim.x + threadIdx.x;
    int node = (int)(gt >> 4);
    int lane = (int)(gt & 15);
    if (node >= N_NODES) return;
    int beg = row_start[node];
    int end = row_start[node + 1];
    int n = end - beg;
    float a[8];
#pragma unroll
    for (int j = 0; j < 8; j++) a[j] = 0.f;
    if (n > 0) {
        const unsigned short* gbase = src + lane * 8;
        int nm1 = n - 1;
        int s[16];
#pragma unroll
        for (int j = 0; j < 16; j++) {
            int jj = (j < nm1) ? j : nm1;          // clamp: always in [beg,end-1]
            s[j] = csr_src[beg + jj];
        }
        uint4 u[16];
#pragma unroll
        for (int j = 0; j < 16; j++)
            u[j] = *(const uint4*)(gbase + (size_t)s[j] * CH);
#pragma unroll
        for (int j = 0; j < 16; j++) {
            if (j < n) {                            // mask dup tail
                acc_u32(u[j].x, a[0], a[1]); acc_u32(u[j].y, a[2], a[3]);
                acc_u32(u[j].z, a[4], a[5]); acc_u32(u[j].w, a[6], a[7]);
            }
        }
        int e = beg + 16;
        while (e + 8 <= end) {
            int s2[8];
#pragma unroll
            for (int j = 0; j < 8; j++) s2[j] = csr_src[e + j];
            uint4 u2[8];
#pragma unroll
            for (int j = 0; j < 8; j++)
                u2[j] = *(const uint4*)(gbase + (size_t)s2[j] * CH);
#pragma unroll
            for (int j = 0; j < 8; j++) {
                acc_u32(u2[j].x, a[0], a[1]); acc_u32(u2[j].y, a[2], a[3]);
                acc_u32(u2[j].z, a[4], a[5]); acc_u32(u2[j].w, a[6], a[7]);
            }
            e += 8;
        }
        while (e < end) {
            int s0 = csr_src[e];
            uint4 u0 = *(const uint4*)(gbase + (size_t)s0 * CH);
            acc_u32(u0.x, a[0], a[1]); acc_u32(u0.y, a[2], a[3]);
            acc_u32(u0.z, a[4], a[5]); acc_u32(u0.w, a[6], a[7]);
            e++;
        }
    }
    float rinv = 1.0f / (float)max(n, 1);
    unsigned int p0 = (unsigned int)f2bf(a[0] * rinv) | ((unsigned int)f2bf(a[1] * rinv) << 16);
    unsigned int p1 = (unsigned int)f2bf(a[2] * rinv) | ((unsigned int)f2bf(a[3] * rinv) << 16);
    unsigned int p2 = (unsigned int)f2bf(a[4] * rinv) | ((unsigned int)f2bf(a[5] * rinv) << 16);
    unsigned int p3 = (unsigned int)f2bf(a[6] * rinv) | ((unsigned int)f2bf(a[7] * rinv) << 16);
    *(uint4*)(mdst + (size_t)node * CH + lane * 8) = make_uint4(p0, p1, p2, p3);
}

// --- MFMA GEMM: r4 verbatim (proven 256.1us structure; r5/r6 A-streaming
// experiments both regressed — A LDS round-trip stays). A = Mb (k<4) ++ Xr
// (k>=4), double-buffered LDS, LDK=40, 40KB -> 4 blocks/CU. ---
#define LDK 40
#define CLS_LD 130
__global__ __launch_bounds__(256) void k_gemm_mfma(
    const unsigned short* __restrict__ Mb,     // [N][CH] mean, bf16
    const unsigned short* __restrict__ Xr,     // [N][CH] root, bf16
    const unsigned short* __restrict__ WT, const void* __restrict__ bias,
    const int* __restrict__ dtf,
    unsigned short* __restrict__ out,          // [N][CH] bf16 or null
    const void* __restrict__ wcls, const void* __restrict__ bcls,
    float* __restrict__ cls_out) {
    __shared__ unsigned short smem[4 * 128 * LDK];   // As dbuf + Bs dbuf (40KB)
    unsigned short* As = smem;
    unsigned short* Bs = smem + 2 * 128 * LDK;
    const int t = threadIdx.x;
    const int w = t >> 6, l = t & 63;
    const int wx = w & 1, wy = w >> 1;
    const int quad = l >> 4, lrow = l & 15;
    const int row0 = blockIdx.x * 128;
    const int srow = t >> 1, shalf = t & 1;
    const int isbf = *dtf;

    int ar = row0 + srow;
    if (ar >= N_NODES) ar = N_NODES - 1;
    const unsigned short* abase_m = Mb + (size_t)ar * CH + shalf * 16;
    const unsigned short* abase_x = Xr + (size_t)ar * CH + shalf * 16;
    const unsigned short* bbase = WT + (size_t)srow * KTOT + shalf * 16;

    v4f acc[4][4];
#pragma unroll
    for (int i = 0; i < 4; i++)
#pragma unroll
        for (int j = 0; j < 4; j++) acc[i][j] = (v4f){0.f, 0.f, 0.f, 0.f};

    {   // prologue: stage step 0 (A from mean)
        uint4 a0 = *(const uint4*)abase_m, a1 = *(const uint4*)(abase_m + 8);
        uint4 b0 = *(const uint4*)bbase, b1 = *(const uint4*)(bbase + 8);
        *(uint4*)&As[srow * LDK + shalf * 16] = a0;
        *(uint4*)&As[srow * LDK + shalf * 16 + 8] = a1;
        *(uint4*)&Bs[srow * LDK + shalf * 16] = b0;
        *(uint4*)&Bs[srow * LDK + shalf * 16 + 8] = b1;
    }
#pragma unroll
    for (int k = 0; k < KTOT / 32; k++) {
        uint4 na0, na1, nb0, nb1;
        if (k < KTOT / 32 - 1) {
            const unsigned short* na = (k < 3) ? (abase_m + (k + 1) * 32)
                                               : (abase_x + (k - 3) * 32);
            na0 = *(const uint4*)na;
            na1 = *(const uint4*)(na + 8);
            nb0 = *(const uint4*)(bbase + (k + 1) * 32);
            nb1 = *(const uint4*)(bbase + (k + 1) * 32 + 8);
        }
        __syncthreads();
        const int cur = (k & 1) * 128 * LDK, nxt = ((k + 1) & 1) * 128 * LDK;
        v8s af[4], bfr[4];
#pragma unroll
        for (int mi = 0; mi < 4; mi++)
            af[mi] = *(const v8s*)&As[cur + (wy * 64 + mi * 16 + lrow) * LDK + quad * 8];
#pragma unroll
        for (int ni = 0; ni < 4; ni++)
            bfr[ni] = *(const v8s*)&Bs[cur + (wx * 64 + ni * 16 + lrow) * LDK + quad * 8];
#pragma unroll
        for (int mi = 0; mi < 4; mi++)
#pragma unroll
            for (int ni = 0; ni < 4; ni++)
                acc[mi][ni] = __builtin_amdgcn_mfma_f32_16x16x32_bf16(
                    af[mi], bfr[ni], acc[mi][ni], 0, 0, 0);
        if (k < KTOT / 32 - 1) {
            *(uint4*)&As[nxt + srow * LDK + shalf * 16] = na0;
            *(uint4*)&As[nxt + srow * LDK + shalf * 16 + 8] = na1;
            *(uint4*)&Bs[nxt + srow * LDK + shalf * 16] = nb0;
            *(uint4*)&Bs[nxt + srow * LDK + shalf * 16 + 8] = nb1;
        }
    }
    float bj[4];
#pragma unroll
    for (int ni = 0; ni < 4; ni++) bj[ni] = ldf(bias, isbf, wx * 64 + ni * 16 + lrow);

    if (!cls_out) {
#pragma unroll
        for (int mi = 0; mi < 4; mi++) {
#pragma unroll
            for (int r = 0; r < 4; r++) {
                int grow = row0 + wy * 64 + mi * 16 + quad * 4 + r;
                if (grow < N_NODES) {
#pragma unroll
                    for (int ni = 0; ni < 4; ni++) {
                        int col = wx * 64 + ni * 16 + lrow;
                        float v = fmaxf(acc[mi][ni][r] + bj[ni], 0.0f);
                        out[(size_t)grow * CH + col] = f2bf(v);
                    }
                }
            }
        }
    } else {
        __syncthreads();   // all waves done with As/Bs -> reuse smem
        float* wcls_s = (float*)(smem + 16896);  // 384 floats @ byte 33792 (<40KB)
        for (int i = t; i < CH * NCLS; i += 256) wcls_s[i] = ldf(wcls, isbf, i);
#pragma unroll
        for (int mi = 0; mi < 4; mi++) {
#pragma unroll
            for (int r = 0; r < 4; r++) {
                int row = wy * 64 + mi * 16 + quad * 4 + r;
#pragma unroll
                for (int ni = 0; ni < 4; ni++) {
                    int col = wx * 64 + ni * 16 + lrow;
                    float v = fmaxf(acc[mi][ni][r] + bj[ni], 0.0f);
                    smem[row * CLS_LD + col] = f2bf(v);
                }
            }
        }
        __syncthreads();
        if (t < 128) {
            int grow = row0 + t;
            if (grow < N_NODES) {
                float a0 = 0.f, a1 = 0.f, a2 = 0.f;
                for (int k = 0; k < CH; k++) {
                    float h = bf2f(smem[t * CLS_LD + k]);
                    a0 += h * wcls_s[k * NCLS + 0];
                    a1 += h * wcls_s[k * NCLS + 1];
                    a2 += h * wcls_s[k * NCLS + 2];
                }
                cls_out[(size_t)grow * NCLS + 0] = a0 + ldf(bcls, isbf, 0);
                cls_out[(size_t)grow * NCLS + 1] = a1 + ldf(bcls, isbf, 1);
                cls_out[(size_t)grow * NCLS + 2] = a2 + ldf(bcls, isbf, 2);
            }
        }
    }
}

extern "C" void kernel_launch(void* const* d_in, const int* in_sizes, int n_in,
                              void* d_out, int out_size, void* d_ws, size_t ws_size,
                              hipStream_t stream) {
    const void* x = d_in[0];
    const void* eidx = d_in[1];
    const void* w_l1 = d_in[2];
    const void* b_l1 = d_in[3];
    const void* w_r1 = d_in[4];
    const void* w_l2 = d_in[5];
    const void* b_l2 = d_in[6];
    const void* w_r2 = d_in[7];
    const void* w_cls = d_in[8];
    const void* b_cls = d_in[9];

    char* w = (char*)d_ws;
    int* eflag = (int*)w;
    int* dtf = (int*)(w + 64);
    int* done = (int*)(w + 128);
    int* hist = (int*)(w + 4096);                            // 192,080 B
    int* bsum = (int*)(w + 196608);                          // 188 B
    int* row_start = (int*)(w + 262144);                     // 400,004 B
    unsigned int* part = (unsigned int*)(w + 720896);        // 4 MB
    int* csr_src = (int*)(w + 4915200);                      // 4 MB
    unsigned short* WT1 = (unsigned short*)(w + 8978432);    // 64 KB
    unsigned short* WT2 = (unsigned short*)(w + 9043968);    // 64 KB
    unsigned short* Xb = (unsigned short*)(w + 11534336);    // 25.6 MB, ends 37,134,336
    unsigned short* Mb = (unsigned short*)(w + 37748736);    // 25.6 MB, ends 63,348,736
    unsigned short* Hb = (unsigned short*)(w + 67108864);    // 25.6 MB, ends 92,708,864

    // K1: hist (245, self-sniffed; block0 publishes eflag/dtf/done) + WT cvt (256)
    hipLaunchKernelGGL(k_A1, dim3(NB_A + 2 * NB_CVTW), dim3(256), 0, stream,
                       eidx, eflag, dtf, done, hist, x,
                       w_l1, w_r1, WT1, w_l2, w_r2, WT2);
    // K2: scan (47) + x-cvt (1000 blocks x 4 tiles)
    hipLaunchKernelGGL(k_scanH, dim3(NB_SCAN + CVT_SCAN / 4), dim3(1024), 0, stream,
                       hist, bsum, done, x, Xb, dtf);
    // K3: scatter (245) + x-cvt (4500 blocks x 1 tile)
    hipLaunchKernelGGL(k_A3, dim3(NB_A + CVT_A3), dim3(256), 0, stream,
                       eidx, eflag, hist, part, x, Xb, dtf);
    // K4: bucket finalize (196) + x-cvt (1000 blocks x 4 tiles)
    hipLaunchKernelGGL(k_B, dim3(NBKT + CVT_B / 4), dim3(1024), 0, stream,
                       hist, part, row_start, csr_src, x, Xb, dtf);
    // layer 1: gather Xb -> Mb, then GEMM (Mb ++ Xb) -> Hb
    hipLaunchKernelGGL(k_agg, dim3(N_NODES * 16 / 256), dim3(256), 0, stream,
                       row_start, csr_src, Xb, Mb);
    hipLaunchKernelGGL(k_gemm_mfma, dim3((N_NODES + 127) / 128), dim3(256), 0, stream,
                       Mb, Xb, WT1, b_l1, dtf, Hb,
                       (const void*)nullptr, (const void*)nullptr, (float*)nullptr);
    // layer 2: gather Hb -> Mb, then GEMM (Mb ++ Hb) + classifier -> logits
    hipLaunchKernelGGL(k_agg, dim3(N_NODES * 16 / 256), dim3(256), 0, stream,
                       row_start, csr_src, Hb, Mb);
    hipLaunchKernelGGL(k_gemm_mfma, dim3((N_NODES + 127) / 128), dim3(256), 0, stream,
                       Mb, Hb, WT2, b_l2, dtf, (unsigned short*)nullptr,
                       w_cls, b_cls, (float*)d_out);
}